// Round 1
// baseline (215.286 us; speedup 1.0000x reference)
//
#include <hip/hip_runtime.h>

#define BLOCK 256
#define GRID 2048

__device__ __forceinline__ int gmgs_cls(float x) {
    // (clip(floor(x), -1, 2) + 1) -> {0,1,2,3}
    float f = fminf(fmaxf(floorf(x), -1.0f), 2.0f);
    return (int)f + 1;
}

__global__ __launch_bounds__(BLOCK) void gmgs_partial_kernel(
    const float* __restrict__ pred,
    const float* __restrict__ tru,
    const float* __restrict__ score,
    float* __restrict__ partials,
    int n4, int rem)
{
    __shared__ float sm_e[16];   // unnormalized exp(-score)
    __shared__ float sred[BLOCK / 64];
    __shared__ float s_inv;

    const int tid = threadIdx.x;

    if (tid < 16) sm_e[tid] = expf(-score[tid]);
    __syncthreads();
    if (tid == 0) {
        float s = 0.0f;
        #pragma unroll
        for (int i = 0; i < 16; ++i) s += sm_e[i];
        s_inv = 1.0f / s;
    }
    __syncthreads();
    const float inv_norm = s_inv;

    const float4* __restrict__ pred4 = (const float4*)pred;
    const float4* __restrict__ tru4  = (const float4*)tru;

    float acc = 0.0f;
    const int stride = gridDim.x * blockDim.x;
    for (int i = blockIdx.x * blockDim.x + tid; i < n4; i += stride) {
        float4 p = pred4[i];
        float4 t = tru4[i];
        #pragma unroll
        for (int k = 0; k < 4; ++k) {
            float pv = (&p.x)[k];
            float tv = (&t.x)[k];
            int pc = gmgs_cls(pv);
            int tc = gmgs_cls(tv);
            float d = pv - tv;
            acc += d * d * sm_e[tc * 4 + pc];
        }
    }

    // scalar tail (n not divisible by 4) handled by block 0
    if (blockIdx.x == 0 && tid < rem) {
        int i = n4 * 4 + tid;
        float pv = pred[i];
        float tv = tru[i];
        int pc = gmgs_cls(pv);
        int tc = gmgs_cls(tv);
        float d = pv - tv;
        acc += d * d * sm_e[tc * 4 + pc];
    }

    // wave64 reduce
    #pragma unroll
    for (int off = 32; off > 0; off >>= 1)
        acc += __shfl_down(acc, off, 64);

    if ((tid & 63) == 0) sred[tid >> 6] = acc;
    __syncthreads();
    if (tid == 0) {
        float s = 0.0f;
        #pragma unroll
        for (int w = 0; w < BLOCK / 64; ++w) s += sred[w];
        partials[blockIdx.x] = s * inv_norm;
    }
}

__global__ __launch_bounds__(1024) void gmgs_final_kernel(
    const float* __restrict__ partials,
    float* __restrict__ out,
    int nblocks, float invB)
{
    __shared__ float sred[1024 / 64];
    const int tid = threadIdx.x;

    float acc = 0.0f;
    for (int i = tid; i < nblocks; i += blockDim.x) acc += partials[i];

    #pragma unroll
    for (int off = 32; off > 0; off >>= 1)
        acc += __shfl_down(acc, off, 64);

    if ((tid & 63) == 0) sred[tid >> 6] = acc;
    __syncthreads();
    if (tid == 0) {
        float s = 0.0f;
        #pragma unroll
        for (int w = 0; w < 1024 / 64; ++w) s += sred[w];
        out[0] = s * invB;
    }
}

extern "C" void kernel_launch(void* const* d_in, const int* in_sizes, int n_in,
                              void* d_out, int out_size, void* d_ws, size_t ws_size,
                              hipStream_t stream) {
    const float* pred  = (const float*)d_in[0];
    const float* tru   = (const float*)d_in[1];
    const float* score = (const float*)d_in[2];
    float* out = (float*)d_out;
    float* partials = (float*)d_ws;

    long long n = (long long)in_sizes[0];   // B*T*1
    int n4  = (int)(n >> 2);
    int rem = (int)(n & 3);
    long long B = n / 48;                   // T = 48 per problem setup
    float invB = 1.0f / (float)B;

    gmgs_partial_kernel<<<GRID, BLOCK, 0, stream>>>(pred, tru, score, partials, n4, rem);
    gmgs_final_kernel<<<1, 1024, 0, stream>>>(partials, out, GRID, invB);
}